// Round 8
// baseline (44.354 us; speedup 1.0000x reference)
//
#include <hip/hip_runtime.h>
#include <math.h>

#define BB 4
#define NN 2048
#define MM 128
#define DD 64
#define NEG_SLOPE 0.2f

#define CH  32                // n per block
#define NCH (NN / CH)         // 64 chunks
#define PSTR (MM + 4)         // p_lds row stride (132 floats, 16B-aligned rows)

// ---------------------------------------------------------------------------
// K1: per (ch, b) block, 1024 threads (16 waves -> 4 waves/SIMD):
//   entry : prefetch fe/adj for this block into regs (hides HBM under proj)
//   phase0: stage fs chunk -> LDS; W_src row -> 64 VGPR; u_r; c_e
//   phase1: hs = fs @ W_src^T in place (2 rows/wave); el; er (all 128 m)
//   phase2: scores p=exp(masked leaky), fully-coalesced (consumes prefetch)
//   phase3: agg: thread owns 4m x 2d over 32 n -> pacc; denom/sfe -> pdn
// ---------------------------------------------------------------------------
__global__ __launch_bounds__(1024, 4) void fused_all_kernel(
        const float* __restrict__ fs, const float* __restrict__ W_src,
        const float* __restrict__ attn_l,
        const float* __restrict__ fd, const float* __restrict__ W_dst,
        const float* __restrict__ attn_r,
        const float* __restrict__ W_edge, const float* __restrict__ attn_e,
        const float* __restrict__ fe, const int* __restrict__ adj,
        float* __restrict__ pacc, float* __restrict__ pdn) {
    int ch = blockIdx.x, b = blockIdx.y;
    int n0 = ch * CH;
    int t = threadIdx.x, lane = t & 63, w = t >> 6;

    __shared__ __align__(16) float fsh[CH * DD];       // 8 KB: fs then hs
    __shared__ __align__(16) float p_lds[CH * PSTR];   // 16.5 KB
    __shared__ float el_lds[CH];
    __shared__ float er_lds[MM];
    __shared__ __align__(16) float u_r[DD];
    __shared__ float dred[8][MM], fred[8][MM];         // 8 KB
    __shared__ float ce_s;

    // ---- entry: prefetch fe/adj (consumed in phase 2) ----
    int m = t & 127, h = t >> 7;                       // h in 0..7
    const float* fe_p = fe + ((size_t)(b * NN + n0)) * MM + m;
    const int* adj_p = adj + ((size_t)(b * NN + n0)) * MM + m;
    float fe_loc[4];
    int adj_loc[4];
#pragma unroll
    for (int j = 0; j < 4; ++j) {
        int n = h * 4 + j;
        fe_loc[j] = fe_p[(size_t)n * MM];
        adj_loc[j] = adj_p[(size_t)n * MM];
    }

    // ---- phase 0 ----
    const float4* fs4 = (const float4*)(fs + ((size_t)(b * NN + n0)) * DD);
    if (t < 512) ((float4*)fsh)[t] = fs4[t];

    float4 wreg[16];
    const float4* w4 = (const float4*)(W_src + (size_t)lane * DD);
#pragma unroll
    for (int k = 0; k < 16; ++k) wreg[k] = w4[k];
    float al = attn_l[lane];

    if (t < 64) {                        // u_r[t] = sum_d attn_r[d]*W_dst[d,t]
        float a = 0.f;
#pragma unroll 8
        for (int dd = 0; dd < DD; ++dd) a += attn_r[dd] * W_dst[dd * DD + t];
        u_r[t] = a;
    } else if (t < 128) {                // c_e (second wave)
        float v = W_edge[lane] * attn_e[lane];
#pragma unroll
        for (int off = 32; off > 0; off >>= 1) v += __shfl_xor(v, off, 64);
        if (lane == 0) ce_s = v;
    }
    __syncthreads();

    // ---- phase 1: er (t<128) + proj (2 rows per wave) ----
    if (t < MM) {
        float a2 = 0.f;
        const float4* fd4 = (const float4*)(fd + (size_t)(b * MM + t) * DD);
        const float4* ur4 = (const float4*)u_r;
#pragma unroll
        for (int k = 0; k < 16; ++k) {
            float4 f = fd4[k], u = ur4[k];
            a2 += f.x * u.x + f.y * u.y + f.z * u.z + f.w * u.w;
        }
        er_lds[t] = a2;
    }
    {
        int r0 = w * 2;                                // rows r0, r0+1
        float acc[2] = {0.f, 0.f};
#pragma unroll 4
        for (int k4 = 0; k4 < 16; ++k4) {
            float4 wk = wreg[k4];
            float4 rv0 = ((const float4*)fsh)[(r0 + 0) * 16 + k4];  // bcast
            float4 rv1 = ((const float4*)fsh)[(r0 + 1) * 16 + k4];
            acc[0] += rv0.x * wk.x + rv0.y * wk.y + rv0.z * wk.z + rv0.w * wk.w;
            acc[1] += rv1.x * wk.x + rv1.y * wk.y + rv1.z * wk.z + rv1.w * wk.w;
        }
#pragma unroll
        for (int rr = 0; rr < 2; ++rr) {
            float e = acc[rr] * al;
#pragma unroll
            for (int off = 32; off > 0; off >>= 1) e += __shfl_xor(e, off, 64);
            if (lane == 0) el_lds[r0 + rr] = e;
        }
        // rows fully consumed by owner wave only; safe in-place overwrite
        fsh[(r0 + 0) * DD + lane] = acc[0];
        fsh[(r0 + 1) * DD + lane] = acc[1];
    }
    __syncthreads();

    // ---- phase 2: scores (uses prefetched fe/adj) ----
    {
        float ce = ce_s;
        float er_m = er_lds[m];
        float dsum = 0.f, fsum = 0.f;
#pragma unroll
        for (int j = 0; j < 4; ++j) {
            int n = h * 4 + j;
            float f = fe_loc[j];
            float s = el_lds[n] + ce * f + er_m;
            s = s > 0.f ? s : NEG_SLOPE * s;
            float p = (adj_loc[j] == 1) ? __expf(s) : 0.f;
            p_lds[n * PSTR + m] = p;
            dsum += p;
            fsum += f * p;
        }
        dred[h][m] = dsum;
        fred[h][m] = fsum;
    }
    __syncthreads();

    // ---- phase 3: aggregation; thread owns m = mq*4+{0..3}, d = dq*2+{0,1}
    {
        int mq = t >> 5, dq = t & 31;
        float a0[4], a1[4];
#pragma unroll
        for (int i = 0; i < 4; ++i) { a0[i] = 0.f; a1[i] = 0.f; }
#pragma unroll 4
        for (int n = 0; n < CH; ++n) {
            float2 hv = *(const float2*)&fsh[n * DD + dq * 2];
            float4 p4 = *(const float4*)&p_lds[n * PSTR + mq * 4];
            a0[0] += p4.x * hv.x; a1[0] += p4.x * hv.y;
            a0[1] += p4.y * hv.x; a1[1] += p4.y * hv.y;
            a0[2] += p4.z * hv.x; a1[2] += p4.z * hv.y;
            a0[3] += p4.w * hv.x; a1[3] += p4.w * hv.y;
        }
        size_t obase = (size_t)(b * NCH + ch) * MM;
#pragma unroll
        for (int mm = 0; mm < 4; ++mm) {
            int m2 = mq * 4 + mm;
            *(float2*)&pacc[(obase + m2) * DD + dq * 2] =
                make_float2(a0[mm], a1[mm]);
        }
        if (t < MM) {
            float dn = 0.f, sf = 0.f;
#pragma unroll
            for (int hh = 0; hh < 8; ++hh) { dn += dred[hh][t]; sf += fred[hh][t]; }
            size_t q2 = (obase + t) * 2;
            pdn[q2] = dn;
            pdn[q2 + 1] = sf;
        }
    }
}

// ---------------------------------------------------------------------------
// K2: out[bm,d] = sigmoid((W_edge[d]*Σsfe + Σacc) / Σdenom) over 64 chunks
// ---------------------------------------------------------------------------
__global__ __launch_bounds__(256) void reduce_kernel(
        const float* __restrict__ pacc, const float* __restrict__ pdn,
        const float* __restrict__ W_edge, float* __restrict__ out) {
    int gid = blockIdx.x * 256 + threadIdx.x;   // 32768
    int d = gid & 63, bm = gid >> 6;
    int b = bm >> 7, m = bm & 127;
    float accs = 0.f, dens = 0.f, sfes = 0.f;
#pragma unroll 8
    for (int ch = 0; ch < NCH; ++ch) {
        size_t idx = (size_t)(b * NCH + ch) * MM + m;
        accs += pacc[idx * DD + d];
        dens += pdn[idx * 2];
        sfes += pdn[idx * 2 + 1];
    }
    float v = (W_edge[d] * sfes + accs) / dens;
    out[(size_t)bm * DD + d] = 1.f / (1.f + __expf(-v));
}

extern "C" void kernel_launch(void* const* d_in, const int* in_sizes, int n_in,
                              void* d_out, int out_size, void* d_ws, size_t ws_size,
                              hipStream_t stream) {
    const float* feat_src  = (const float*)d_in[0];
    const float* feat_dst  = (const float*)d_in[1];
    const float* feat_edge = (const float*)d_in[2];
    const int*   adj       = (const int*)d_in[3];
    const float* W_src     = (const float*)d_in[4];
    const float* W_dst     = (const float*)d_in[5];
    const float* W_edge    = (const float*)d_in[6];
    const float* attn_l    = (const float*)d_in[7];
    const float* attn_r    = (const float*)d_in[8];
    const float* attn_e    = (const float*)d_in[9];
    float* out = (float*)d_out;

    float* ws   = (float*)d_ws;
    float* pacc = ws;                                   // 4*64*128*64 = 2097152
    float* pdn  = pacc + (size_t)BB * NCH * MM * DD;    // 65536

    fused_all_kernel<<<dim3(NCH, BB), 1024, 0, stream>>>(
        feat_src, W_src, attn_l, feat_dst, W_dst, attn_r,
        W_edge, attn_e, feat_edge, adj, pacc, pdn);
    reduce_kernel<<<128, 256, 0, stream>>>(pacc, pdn, W_edge, out);
}